// Round 12
// baseline (458.419 us; speedup 1.0000x reference)
//
#include <hip/hip_runtime.h>
#include <hip/hip_bf16.h>

#define NN 50000
#define NR 8
#define DIM 128
#define NE 800000
#define TM 32     // targets per block
#define PAD 136   // A-tile row stride in bf16 (128 + 8): 2-way LDS conflicts only (free)
#define NB 1563   // ceil(NN/TM)

using floatx4 = __attribute__((ext_vector_type(4))) float;
using bf16x8  = __attribute__((ext_vector_type(8))) __bf16;

// ---------------- workspace layout (in floats) ----------------
// zeroed region: [0, 802304) = cnt + wsum + S2X1 + part/partpre/done
#define OFF_CNT   0u         // 400000: int counts -> float inv in place (seg = t*8+r)
#define OFF_WSUM  400000u    // 400000: wsum[r*NN+h] fp32 atomic accum
#define OFF_S2    800000u    // 1152: S2[1024] + X1[128] (atomic finish)
#define OFF_PART  801152u    // 391 ints: per-chunk sums
#define OFF_PPRE  801664u    // 391 ints: exclusive chunk prefixes (last scanA block)
#define OFF_DONE  802176u    // 2 ints: done counters (scanA, s2redfin)
#define OFF_OFFS  802304u    // 400000 ints: chunk-local CSR offsets (end after fillw)
#define OFF_EH    1202304u   // 800000 ints: CSR-sorted edge head indices
#define OFF_XB    2002304u   // 6.4M bf16: x_emb in bf16 (16B aligned)
#define OFF_WF    5202304u   // 9*2048*8 bf16: weights in MFMA frag order
#define OFF_S2P   5276032u   // NB*1152: per-block S2/X1 partials
// total 7,076,608 floats = 28.3 MB

// ---------------- merged prep: bf16 cast + weight frags + (t,rel) counts ----------------
__global__ __launch_bounds__(256) void prep_k(
    const float* __restrict__ x, __bf16* __restrict__ xb,
    const float* __restrict__ W1, const float* __restrict__ root1, __bf16* __restrict__ wf,
    const int* __restrict__ r, const int* __restrict__ t, int* __restrict__ cnt)
{
    const int gid = blockIdx.x * 256 + threadIdx.x;
    const int nthr = gridDim.x * 256;

    if (gid < 9 * 2048) {
        int mat = gid >> 11, idx = gid & 2047;
        const float* B = (mat < 8) ? (W1 + (size_t)mat * DIM * DIM) : root1;
        int lt = idx & 63, fid = idx >> 6;
        int s = fid >> 3, nt = fid & 7;
        int n = nt * 16 + (lt & 15);
        int kb = s * 32 + (lt >> 4) * 8;
        bf16x8 v;
#pragma unroll
        for (int j = 0; j < 8; ++j) v[j] = (__bf16)B[(kb + j) * DIM + n];
        *reinterpret_cast<bf16x8*>(wf + ((size_t)mat * 2048 + idx) * 8) = v;
    }
    for (int i = gid; i < NN * DIM / 4; i += nthr) {
        int base = i * 4;
        float4 v = *reinterpret_cast<const float4*>(x + base);
        __bf16 o[4] = {(__bf16)v.x, (__bf16)v.y, (__bf16)v.z, (__bf16)v.w};
        *reinterpret_cast<uint2*>(xb + base) = *reinterpret_cast<uint2*>(o);
    }
    for (int i = gid; i < NE / 4; i += nthr) {
        int base = i * 4;
        int4 rv = *reinterpret_cast<const int4*>(r + base);
        int4 tv = *reinterpret_cast<const int4*>(t + base);
        atomicAdd(&cnt[tv.x * NR + rv.x], 1);
        atomicAdd(&cnt[tv.y * NR + rv.y], 1);
        atomicAdd(&cnt[tv.z * NR + rv.z], 1);
        atomicAdd(&cnt[tv.w * NR + rv.w], 1);
    }
}

// ---------------- scan: chunk-local exclusive offsets + inv; last block scans chunk sums ----------------
__global__ __launch_bounds__(256) void scanA_k(const int* cnt, float* invout,
                                               int* __restrict__ offs, int* __restrict__ part,
                                               int* __restrict__ partpre, int* __restrict__ done) {
    __shared__ int lds[512];
    __shared__ int isLast;
    const int tid = threadIdx.x, bid = blockIdx.x;
    const int base = bid * 1024 + tid * 4;
    int v[4] = {0, 0, 0, 0};
    if (base + 3 < NR * NN) {
        int4 q = *reinterpret_cast<const int4*>(cnt + base);
        v[0] = q.x; v[1] = q.y; v[2] = q.z; v[3] = q.w;
    } else {
#pragma unroll
        for (int j = 0; j < 4; ++j) if (base + j < NR * NN) v[j] = cnt[base + j];
    }
    int tsum = v[0] + v[1] + v[2] + v[3];
    lds[tid] = tsum;
    __syncthreads();
#pragma unroll
    for (int off = 1; off < 256; off <<= 1) {
        int val = (tid >= off) ? lds[tid - off] : 0;
        __syncthreads();
        if (tid >= off) lds[tid] += val;
        __syncthreads();
    }
    int run = lds[tid] - tsum;   // chunk-local exclusive
#pragma unroll
    for (int j = 0; j < 4; ++j) {
        if (base + j < NR * NN) {
            offs[base + j] = run;
            invout[base + j] = 1.0f / (float)(v[j] > 1 ? v[j] : 1);
        }
        run += v[j];
    }
    if (tid == 255)
        __hip_atomic_store(&part[bid], lds[255], __ATOMIC_RELEASE, __HIP_MEMORY_SCOPE_AGENT);
    __syncthreads();
    if (tid == 0) {
        int old = atomicAdd(done, 1);
        isLast = (old == 390);
    }
    __syncthreads();
    if (!isLast) return;
    int a = (tid < 391) ? __hip_atomic_load(&part[tid], __ATOMIC_ACQUIRE, __HIP_MEMORY_SCOPE_AGENT) : 0;
    int b = (tid + 256 < 391) ? __hip_atomic_load(&part[tid + 256], __ATOMIC_ACQUIRE, __HIP_MEMORY_SCOPE_AGENT) : 0;
    lds[tid] = a; lds[tid + 256] = b;
    __syncthreads();
#pragma unroll
    for (int off = 1; off < 512; off <<= 1) {
        int x0 = (tid >= off) ? lds[tid - off] : 0;
        int x1 = lds[tid + 256 - off];
        __syncthreads();
        if (tid >= off) lds[tid] += x0;
        lds[tid + 256] += x1;
        __syncthreads();
    }
    if (tid < 391) partpre[tid] = lds[tid] - a;
    if (tid + 256 < 391) partpre[tid + 256] = lds[tid + 256] - b;
}

// ---------------- merged CSR fill + wsum, 4 edges/thread ----------------
__global__ void fillw_k(const int* __restrict__ h, const int* __restrict__ r, const int* __restrict__ t,
                        int* __restrict__ offs, const int* __restrict__ partpre, int* __restrict__ eh,
                        const float* __restrict__ inv, float* __restrict__ wsum) {
    int base = (blockIdx.x * 256 + threadIdx.x) * 4;
    if (base + 3 < NE) {
        int4 hv = *reinterpret_cast<const int4*>(h + base);
        int4 rv = *reinterpret_cast<const int4*>(r + base);
        int4 tv = *reinterpret_cast<const int4*>(t + base);
        int g0 = tv.x * NR + rv.x, g1 = tv.y * NR + rv.y;
        int g2 = tv.z * NR + rv.z, g3 = tv.w * NR + rv.w;
        int p0 = atomicAdd(&offs[g0], 1) + partpre[g0 >> 10];
        int p1 = atomicAdd(&offs[g1], 1) + partpre[g1 >> 10];
        int p2 = atomicAdd(&offs[g2], 1) + partpre[g2 >> 10];
        int p3 = atomicAdd(&offs[g3], 1) + partpre[g3 >> 10];
        eh[p0] = hv.x; eh[p1] = hv.y; eh[p2] = hv.z; eh[p3] = hv.w;
        atomicAdd(&wsum[rv.x * NN + hv.x], inv[g0]);
        atomicAdd(&wsum[rv.y * NN + hv.y], inv[g1]);
        atomicAdd(&wsum[rv.z * NN + hv.z], inv[g2]);
        atomicAdd(&wsum[rv.w * NN + hv.w], inv[g3]);
    } else {
        for (int e = base; e < NE; ++e) {
            int he = h[e], re = r[e];
            int seg = t[e] * NR + re;
            int pos = atomicAdd(&offs[seg], 1) + partpre[seg >> 10];
            eh[pos] = he;
            atomicAdd(&wsum[re * NN + he], inv[seg]);
        }
    }
}

// ---------------- fused layer 1 + layer-2 partials, 32-row tiles ----------------
// R11 core; __launch_bounds__(256,6): kernel compiles to 64 VGPRs (measured R11),
// 85-VGPR budget leaves headroom -> no spill; LDS 21 KB x 6 = 126 KB -> 6 blocks/CU.
__global__ __launch_bounds__(256, 6) void rgcn_fused_k(
    const int* __restrict__ offs, const int* __restrict__ partpre, const int* __restrict__ eh,
    const float* __restrict__ inv, const __bf16* __restrict__ xb, const __bf16* __restrict__ wf,
    const float* __restrict__ b1, const float* __restrict__ wsum,
    float* __restrict__ S2P)
{
    __shared__ __attribute__((aligned(16))) __bf16 Atile[2][TM * PAD];  // 17.4 KB (reused as red[4][576])
    __shared__ int   loffs[TM * NR + 1];
    __shared__ float invl[TM * NR];
    __shared__ float wsl[NR][TM];
    const int tid = threadIdx.x;
    const int wave = tid >> 6, lane = tid & 63, quad = lane >> 4;
    const int slot = tid >> 4, sl = tid & 15;   // 16 gather slots x 16 lanes
    const int tbase = blockIdx.x * TM;
    const int segbase = tbase * NR;

    for (int j = tid; j < TM * NR + 1; j += 256) {
        int g = segbase + j - 1;
        if (g < 0) { loffs[j] = 0; }
        else {
            int gc = g > NR * NN - 1 ? NR * NN - 1 : g;
            loffs[j] = offs[gc] + partpre[gc >> 10];   // global end-offset
        }
    }
    for (int j = tid; j < TM * NR; j += 256) {
        int g = segbase + j;
        invl[j] = (g < NR * NN) ? inv[g] : 0.f;
    }
    if (tid < NR * TM) {
        int rr = tid >> 5, n = tbase + (tid & 31);
        wsl[rr][tid & 31] = (n < NN) ? wsum[rr * NN + n] : 0.f;
    }
    __syncthreads();

    floatx4 C[4];
#pragma unroll
    for (int i = 0; i < 4; ++i) C[i] = (floatx4)0.f;
    const int arow = (wave & 1) * 16 + (lane & 15);   // wave row-strip
    const int ntg0 = (wave >> 1) * 4;                 // wave col-strip (4 nt each)

    // ---- 4 term-pairs: 4 depth-2-pipelined walks (2 rows x 2 terms), 2 A-tiles ----
    for (int tp = 0; tp < 4; ++tp) {
        int st[4], ln[4];
        float a[4][8];
#pragma unroll
        for (int q = 0; q < 4; ++q) {
            int j = (slot + (q >> 1) * 16) * 8 + tp * 2 + (q & 1);
            st[q] = loffs[j];                 // global CSR start
            ln[q] = loffs[j + 1] - loffs[j];
#pragma unroll
            for (int k = 0; k < 8; ++k) a[q][k] = 0.f;
        }
        int mx = max(max(ln[0], ln[1]), max(ln[2], ln[3]));
        if (mx > 0) {
            bf16x8 ycur[4];
#pragma unroll
            for (int q = 0; q < 4; ++q) {
                if (0 < ln[q]) {
                    int he = eh[st[q]];
                    ycur[q] = *reinterpret_cast<const bf16x8*>(xb + (size_t)he * DIM + sl * 8);
                }
            }
            for (int p = 0; p < mx; ++p) {
                bf16x8 ynext[4];
#pragma unroll
                for (int q = 0; q < 4; ++q) {
                    if (p + 1 < ln[q]) {
                        int he = eh[st[q] + p + 1];
                        ynext[q] = *reinterpret_cast<const bf16x8*>(xb + (size_t)he * DIM + sl * 8);
                    }
                }
#pragma unroll
                for (int q = 0; q < 4; ++q) {
                    if (p < ln[q]) {
#pragma unroll
                        for (int k = 0; k < 8; ++k) a[q][k] += (float)ycur[q][k];
                    }
                }
#pragma unroll
                for (int q = 0; q < 4; ++q) ycur[q] = ynext[q];
            }
        }
#pragma unroll
        for (int q = 0; q < 4; ++q) {
            int trow = slot + (q >> 1) * 16;
            float sc = invl[trow * 8 + tp * 2 + (q & 1)];
            bf16x8 out;
#pragma unroll
            for (int k = 0; k < 8; ++k) out[k] = (__bf16)(a[q][k] * sc);
            *reinterpret_cast<bf16x8*>(&Atile[q & 1][trow * PAD + sl * 8]) = out;
        }
        __syncthreads();
#pragma unroll
        for (int u = 0; u < 2; ++u) {
            const __bf16* wterm = wf + (size_t)(tp * 2 + u) * 2048 * 8;
#pragma unroll
            for (int s = 0; s < 4; ++s) {
                bf16x8 af = *reinterpret_cast<const bf16x8*>(&Atile[u][arow * PAD + s * 32 + quad * 8]);
#pragma unroll
                for (int nt = 0; nt < 4; ++nt) {
                    bf16x8 bf = *reinterpret_cast<const bf16x8*>(
                        wterm + (size_t)((s * 8 + ntg0 + nt) * 64 + lane) * 8);
                    C[nt] = __builtin_amdgcn_mfma_f32_16x16x32_bf16(af, bf, C[nt], 0, 0, 0);
                }
            }
        }
        __syncthreads();
    }

    // ---- root term: A row = xb[t] ----
#pragma unroll
    for (int i = 0; i < 2; ++i) {
        int trow = slot + i * 16;
        int t = tbase + trow;
        bf16x8 out;
        if (t < NN) {
            out = *reinterpret_cast<const bf16x8*>(xb + (size_t)t * DIM + sl * 8);
        } else {
#pragma unroll
            for (int j = 0; j < 8; ++j) out[j] = (__bf16)0.f;
        }
        *reinterpret_cast<bf16x8*>(&Atile[0][trow * PAD + sl * 8]) = out;
    }
    __syncthreads();
    {
        const __bf16* wterm = wf + (size_t)8 * 2048 * 8;
#pragma unroll
        for (int s = 0; s < 4; ++s) {
            bf16x8 af = *reinterpret_cast<const bf16x8*>(&Atile[0][arow * PAD + s * 32 + quad * 8]);
#pragma unroll
            for (int nt = 0; nt < 4; ++nt) {
                bf16x8 bf = *reinterpret_cast<const bf16x8*>(
                    wterm + (size_t)((s * 8 + ntg0 + nt) * 64 + lane) * 8);
                C[nt] = __builtin_amdgcn_mfma_f32_16x16x32_bf16(af, bf, C[nt], 0, 0, 0);
            }
        }
    }
    __syncthreads();   // Atile dead -> reuse as reduction scratch

    // ---- epilogue: bias + relu in-register, fused S2/X1 block partials ----
    float* red = reinterpret_cast<float*>(&Atile[0][0]);   // [4][576] = 9.2 KB
    const int rowl0 = (wave & 1) * 16 + quad * 4;
    const int colc = lane & 15;
#pragma unroll
    for (int nt = 0; nt < 4; ++nt) {
        float badd = b1[ntg0 * 16 + nt * 16 + colc];
#pragma unroll
        for (int i = 0; i < 4; ++i) C[nt][i] = fmaxf(C[nt][i] + badd, 0.f);
    }
    float rmask[4];
#pragma unroll
    for (int i = 0; i < 4; ++i) rmask[i] = (tbase + rowl0 + i < NN) ? 1.f : 0.f;
#pragma unroll
    for (int nt = 0; nt < 4; ++nt) {
        float p = rmask[0] * C[nt][0] + rmask[1] * C[nt][1] + rmask[2] * C[nt][2] + rmask[3] * C[nt][3];
        p += __shfl_xor(p, 16);
        p += __shfl_xor(p, 32);
        if (quad == 0) red[wave * 576 + nt * 16 + colc] = p;
    }
#pragma unroll
    for (int rr = 0; rr < NR; ++rr) {
        float w0 = wsl[rr][rowl0], w1 = wsl[rr][rowl0 + 1];
        float w2 = wsl[rr][rowl0 + 2], w3 = wsl[rr][rowl0 + 3];
#pragma unroll
        for (int nt = 0; nt < 4; ++nt) {
            float p = w0 * C[nt][0] + w1 * C[nt][1] + w2 * C[nt][2] + w3 * C[nt][3];
            p += __shfl_xor(p, 16);
            p += __shfl_xor(p, 32);
            if (quad == 0) red[wave * 576 + 64 + rr * 64 + nt * 16 + colc] = p;
        }
    }
    __syncthreads();
    for (int j = tid; j < 1152; j += 256) {
        int rr = j >> 7, c = j & 127;          // rr==8 -> X1
        int u = c >> 6, cc = c & 63;
        int o = (rr < 8) ? (64 + rr * 64 + cc) : cc;
        S2P[(size_t)blockIdx.x * 1152 + j] = red[(u * 2) * 576 + o] + red[(u * 2 + 1) * 576 + o];
    }
}

// ---------------- s2red + final merged: reduce S2P -> S2X1, last block computes out ----------------
__global__ __launch_bounds__(256) void s2redfin_k(
    const float* __restrict__ S2P, float* __restrict__ S2X1, int* __restrict__ done,
    const float* __restrict__ W2, const float* __restrict__ root2,
    const float* __restrict__ b2, float* __restrict__ out)
{
    __shared__ float s2l[1152];
    __shared__ float red2[256];
    __shared__ int isLast;
    const int tid = threadIdx.x;
    int cb = blockIdx.x % 5, stripe = blockIdx.x / 5;
    int c = cb * 256 + tid;
    if (c < 1152) {
        int b0 = stripe * 196, b1 = min(NB, b0 + 196);
        float s0 = 0.f, s1 = 0.f;
        int b = b0;
        for (; b + 1 < b1; b += 2) {
            s0 += S2P[(size_t)b * 1152 + c];
            s1 += S2P[(size_t)(b + 1) * 1152 + c];
        }
        if (b < b1) s0 += S2P[(size_t)b * 1152 + c];
        atomicAdd(&S2X1[c], s0 + s1);
    }
    __threadfence();
    __syncthreads();
    if (tid == 0) {
        int old = atomicAdd(done, 1);
        isLast = (old == 39);
    }
    __syncthreads();
    if (!isLast) return;
    for (int j = tid; j < 1152; j += 256)
        s2l[j] = __hip_atomic_load(&S2X1[j], __ATOMIC_ACQUIRE, __HIP_MEMORY_SCOPE_AGENT);
    __syncthreads();
    const int o = tid & 127, half = tid >> 7;
    float s = 0.f;
    for (int j = half * 576; j < (half + 1) * 576; ++j) {
        float w = (j < 1024) ? W2[(size_t)j * DIM + o] : root2[(size_t)(j - 1024) * DIM + o];
        s += s2l[j] * w;
    }
    red2[tid] = s;
    __syncthreads();
    if (half == 0) out[o] = (red2[o] + red2[o + 128]) * (1.0f / NN) + b2[o];
}

extern "C" void kernel_launch(void* const* d_in, const int* in_sizes, int n_in,
                              void* d_out, int out_size, void* d_ws, size_t ws_size,
                              hipStream_t stream)
{
    const int*   h     = (const int*)d_in[0];
    const int*   r     = (const int*)d_in[1];
    const int*   t     = (const int*)d_in[2];
    const float* x_emb = (const float*)d_in[3];
    const float* W1    = (const float*)d_in[4];
    const float* root1 = (const float*)d_in[5];
    const float* b1    = (const float*)d_in[6];
    const float* W2    = (const float*)d_in[7];
    const float* root2 = (const float*)d_in[8];
    const float* b2    = (const float*)d_in[9];

    float* ws    = (float*)d_ws;
    float* cnt   = ws + OFF_CNT;     // int counts then inv floats in place
    float* wsum  = ws + OFF_WSUM;
    float* S2    = ws + OFF_S2;      // 1024 S2 + 128 X1 contiguous
    int*   part  = (int*)(ws + OFF_PART);
    int*   ppre  = (int*)(ws + OFF_PPRE);
    int*   done  = (int*)(ws + OFF_DONE);
    int*   offs  = (int*)(ws + OFF_OFFS);
    int*   eh    = (int*)(ws + OFF_EH);
    __bf16* xb   = (__bf16*)(ws + OFF_XB);
    __bf16* wf   = (__bf16*)(ws + OFF_WF);
    float* S2P   = ws + OFF_S2P;

    // zero counts + wsum + S2X1 + part/partpre/done (re-poisoned to 0xAA before every timed launch)
    hipMemsetAsync(ws, 0, (size_t)802304 * sizeof(float), stream);

    // merged cast + weight-frag + count
    prep_k<<<1600, 256, 0, stream>>>(x_emb, xb, W1, root1, wf, r, t, (int*)cnt);

    // chunk-local scan + last-block chunk-prefix scan
    scanA_k<<<391, 256, 0, stream>>>((const int*)cnt, cnt, offs, part, ppre, done);

    // merged fill + wsum single edge pass (4 edges/thread)
    fillw_k<<<782, 256, 0, stream>>>(h, r, t, offs, ppre, eh, cnt, wsum);

    // fused layer 1 + layer-2 partials, depth-2-pipelined walks, 6 blocks/CU
    rgcn_fused_k<<<NB, 256, 0, stream>>>(offs, ppre, eh, cnt, xb, wf, b1, wsum, S2P);

    // reduce + final GEMV (last-block pattern)
    s2redfin_k<<<40, 256, 0, stream>>>(S2P, S2, done + 1, W2, root2, b2, (float*)d_out);
}

// Round 13
// 453.910 us; speedup vs baseline: 1.0099x; 1.0099x over previous
//
#include <hip/hip_runtime.h>
#include <hip/hip_bf16.h>

#define NN 50000
#define NR 8
#define DIM 128
#define NE 800000
#define TM 32     // targets per block
#define PAD 136   // A-tile row stride in bf16 (128 + 8): 2-way LDS conflicts only (free)
#define NB 1563   // ceil(NN/TM)

using floatx4 = __attribute__((ext_vector_type(4))) float;
using bf16x8  = __attribute__((ext_vector_type(8))) __bf16;

// ---------------- workspace layout (in floats) ----------------
// zeroed region: [0, 802304) = cnt + wsum + S2X1 + part/partpre/done
#define OFF_CNT   0u         // 400000: int counts -> float inv in place (seg = t*8+r)
#define OFF_WSUM  400000u    // 400000: wsum[r*NN+h] fp32 atomic accum
#define OFF_S2    800000u    // 1152: S2[1024] + X1[128] (atomic finish)
#define OFF_PART  801152u    // 391 ints: per-chunk sums
#define OFF_PPRE  801664u    // 391 ints: exclusive chunk prefixes (last scanA block)
#define OFF_DONE  802176u    // 2 ints: done counters (scanA, s2redfin)
#define OFF_OFFS  802304u    // 400000 ints: chunk-local CSR offsets (end after fillw)
#define OFF_EH    1202304u   // 800000 ints: CSR-sorted edge head indices
#define OFF_XB    2002304u   // 6.4M bf16: x_emb in bf16 (16B aligned)
#define OFF_WF    5202304u   // 9*2048*8 bf16: weights in MFMA frag order
#define OFF_S2P   5276032u   // NB*1152: per-block S2/X1 partials
// total 7,076,608 floats = 28.3 MB

// ---------------- merged prep: bf16 cast + weight frags + (t,rel) counts ----------------
__global__ __launch_bounds__(256) void prep_k(
    const float* __restrict__ x, __bf16* __restrict__ xb,
    const float* __restrict__ W1, const float* __restrict__ root1, __bf16* __restrict__ wf,
    const int* __restrict__ r, const int* __restrict__ t, int* __restrict__ cnt)
{
    const int gid = blockIdx.x * 256 + threadIdx.x;
    const int nthr = gridDim.x * 256;

    if (gid < 9 * 2048) {
        int mat = gid >> 11, idx = gid & 2047;
        const float* B = (mat < 8) ? (W1 + (size_t)mat * DIM * DIM) : root1;
        int lt = idx & 63, fid = idx >> 6;
        int s = fid >> 3, nt = fid & 7;
        int n = nt * 16 + (lt & 15);
        int kb = s * 32 + (lt >> 4) * 8;
        bf16x8 v;
#pragma unroll
        for (int j = 0; j < 8; ++j) v[j] = (__bf16)B[(kb + j) * DIM + n];
        *reinterpret_cast<bf16x8*>(wf + ((size_t)mat * 2048 + idx) * 8) = v;
    }
    for (int i = gid; i < NN * DIM / 4; i += nthr) {
        int base = i * 4;
        float4 v = *reinterpret_cast<const float4*>(x + base);
        __bf16 o[4] = {(__bf16)v.x, (__bf16)v.y, (__bf16)v.z, (__bf16)v.w};
        *reinterpret_cast<uint2*>(xb + base) = *reinterpret_cast<uint2*>(o);
    }
    for (int i = gid; i < NE / 4; i += nthr) {
        int base = i * 4;
        int4 rv = *reinterpret_cast<const int4*>(r + base);
        int4 tv = *reinterpret_cast<const int4*>(t + base);
        atomicAdd(&cnt[tv.x * NR + rv.x], 1);
        atomicAdd(&cnt[tv.y * NR + rv.y], 1);
        atomicAdd(&cnt[tv.z * NR + rv.z], 1);
        atomicAdd(&cnt[tv.w * NR + rv.w], 1);
    }
}

// ---------------- scan: chunk-local exclusive offsets + inv; last block scans chunk sums ----------------
__global__ __launch_bounds__(256) void scanA_k(const int* cnt, float* invout,
                                               int* __restrict__ offs, int* __restrict__ part,
                                               int* __restrict__ partpre, int* __restrict__ done) {
    __shared__ int lds[512];
    __shared__ int isLast;
    const int tid = threadIdx.x, bid = blockIdx.x;
    const int base = bid * 1024 + tid * 4;
    int v[4] = {0, 0, 0, 0};
    if (base + 3 < NR * NN) {
        int4 q = *reinterpret_cast<const int4*>(cnt + base);
        v[0] = q.x; v[1] = q.y; v[2] = q.z; v[3] = q.w;
    } else {
#pragma unroll
        for (int j = 0; j < 4; ++j) if (base + j < NR * NN) v[j] = cnt[base + j];
    }
    int tsum = v[0] + v[1] + v[2] + v[3];
    lds[tid] = tsum;
    __syncthreads();
#pragma unroll
    for (int off = 1; off < 256; off <<= 1) {
        int val = (tid >= off) ? lds[tid - off] : 0;
        __syncthreads();
        if (tid >= off) lds[tid] += val;
        __syncthreads();
    }
    int run = lds[tid] - tsum;   // chunk-local exclusive
#pragma unroll
    for (int j = 0; j < 4; ++j) {
        if (base + j < NR * NN) {
            offs[base + j] = run;
            invout[base + j] = 1.0f / (float)(v[j] > 1 ? v[j] : 1);
        }
        run += v[j];
    }
    if (tid == 255)
        __hip_atomic_store(&part[bid], lds[255], __ATOMIC_RELEASE, __HIP_MEMORY_SCOPE_AGENT);
    __syncthreads();
    if (tid == 0) {
        int old = atomicAdd(done, 1);
        isLast = (old == 390);
    }
    __syncthreads();
    if (!isLast) return;
    int a = (tid < 391) ? __hip_atomic_load(&part[tid], __ATOMIC_ACQUIRE, __HIP_MEMORY_SCOPE_AGENT) : 0;
    int b = (tid + 256 < 391) ? __hip_atomic_load(&part[tid + 256], __ATOMIC_ACQUIRE, __HIP_MEMORY_SCOPE_AGENT) : 0;
    lds[tid] = a; lds[tid + 256] = b;
    __syncthreads();
#pragma unroll
    for (int off = 1; off < 512; off <<= 1) {
        int x0 = (tid >= off) ? lds[tid - off] : 0;
        int x1 = lds[tid + 256 - off];
        __syncthreads();
        if (tid >= off) lds[tid] += x0;
        lds[tid + 256] += x1;
        __syncthreads();
    }
    if (tid < 391) partpre[tid] = lds[tid] - a;
    if (tid + 256 < 391) partpre[tid + 256] = lds[tid + 256] - b;
}

// ---------------- merged CSR fill + wsum, 4 edges/thread ----------------
__global__ void fillw_k(const int* __restrict__ h, const int* __restrict__ r, const int* __restrict__ t,
                        int* __restrict__ offs, const int* __restrict__ partpre, int* __restrict__ eh,
                        const float* __restrict__ inv, float* __restrict__ wsum) {
    int base = (blockIdx.x * 256 + threadIdx.x) * 4;
    if (base + 3 < NE) {
        int4 hv = *reinterpret_cast<const int4*>(h + base);
        int4 rv = *reinterpret_cast<const int4*>(r + base);
        int4 tv = *reinterpret_cast<const int4*>(t + base);
        int g0 = tv.x * NR + rv.x, g1 = tv.y * NR + rv.y;
        int g2 = tv.z * NR + rv.z, g3 = tv.w * NR + rv.w;
        int p0 = atomicAdd(&offs[g0], 1) + partpre[g0 >> 10];
        int p1 = atomicAdd(&offs[g1], 1) + partpre[g1 >> 10];
        int p2 = atomicAdd(&offs[g2], 1) + partpre[g2 >> 10];
        int p3 = atomicAdd(&offs[g3], 1) + partpre[g3 >> 10];
        eh[p0] = hv.x; eh[p1] = hv.y; eh[p2] = hv.z; eh[p3] = hv.w;
        atomicAdd(&wsum[rv.x * NN + hv.x], inv[g0]);
        atomicAdd(&wsum[rv.y * NN + hv.y], inv[g1]);
        atomicAdd(&wsum[rv.z * NN + hv.z], inv[g2]);
        atomicAdd(&wsum[rv.w * NN + hv.w], inv[g3]);
    } else {
        for (int e = base; e < NE; ++e) {
            int he = h[e], re = r[e];
            int seg = t[e] * NR + re;
            int pos = atomicAdd(&offs[seg], 1) + partpre[seg >> 10];
            eh[pos] = he;
            atomicAdd(&wsum[re * NN + he], inv[seg]);
        }
    }
}

// ---------------- fused layer 1 + layer-2 partials, 32-row tiles ----------------
// R11 core. __launch_bounds__(256,5): budget floor(512/5)=102 VGPRs >= the 64 this
// kernel needs (measured R11) -> no spill pressure, 5 blocks/CU (LDS 21KB*5=105KB).
// NOTE: (256,6) [budget 85] made the allocator crush to 40 VGPRs + scratch spills
// (R12: WRITE 7->136MB). Keep budget comfortably above need.
__global__ __launch_bounds__(256, 5) void rgcn_fused_k(
    const int* __restrict__ offs, const int* __restrict__ partpre, const int* __restrict__ eh,
    const float* __restrict__ inv, const __bf16* __restrict__ xb, const __bf16* __restrict__ wf,
    const float* __restrict__ b1, const float* __restrict__ wsum,
    float* __restrict__ S2P)
{
    __shared__ __attribute__((aligned(16))) __bf16 Atile[2][TM * PAD];  // 17.4 KB (reused as red[4][576])
    __shared__ int   loffs[TM * NR + 1];
    __shared__ float invl[TM * NR];
    __shared__ float wsl[NR][TM];
    const int tid = threadIdx.x;
    const int wave = tid >> 6, lane = tid & 63, quad = lane >> 4;
    const int slot = tid >> 4, sl = tid & 15;   // 16 gather slots x 16 lanes
    const int tbase = blockIdx.x * TM;
    const int segbase = tbase * NR;

    for (int j = tid; j < TM * NR + 1; j += 256) {
        int g = segbase + j - 1;
        if (g < 0) { loffs[j] = 0; }
        else {
            int gc = g > NR * NN - 1 ? NR * NN - 1 : g;
            loffs[j] = offs[gc] + partpre[gc >> 10];   // global end-offset
        }
    }
    for (int j = tid; j < TM * NR; j += 256) {
        int g = segbase + j;
        invl[j] = (g < NR * NN) ? inv[g] : 0.f;
    }
    if (tid < NR * TM) {
        int rr = tid >> 5, n = tbase + (tid & 31);
        wsl[rr][tid & 31] = (n < NN) ? wsum[rr * NN + n] : 0.f;
    }
    __syncthreads();

    floatx4 C[4];
#pragma unroll
    for (int i = 0; i < 4; ++i) C[i] = (floatx4)0.f;
    const int arow = (wave & 1) * 16 + (lane & 15);   // wave row-strip
    const int ntg0 = (wave >> 1) * 4;                 // wave col-strip (4 nt each)

    // ---- 4 term-pairs: 4 depth-2-pipelined walks (2 rows x 2 terms), 2 A-tiles ----
    for (int tp = 0; tp < 4; ++tp) {
        int st[4], ln[4];
        float a[4][8];
#pragma unroll
        for (int q = 0; q < 4; ++q) {
            int j = (slot + (q >> 1) * 16) * 8 + tp * 2 + (q & 1);
            st[q] = loffs[j];                 // global CSR start
            ln[q] = loffs[j + 1] - loffs[j];
#pragma unroll
            for (int k = 0; k < 8; ++k) a[q][k] = 0.f;
        }
        int mx = max(max(ln[0], ln[1]), max(ln[2], ln[3]));
        if (mx > 0) {
            bf16x8 ycur[4];
#pragma unroll
            for (int q = 0; q < 4; ++q) {
                if (0 < ln[q]) {
                    int he = eh[st[q]];
                    ycur[q] = *reinterpret_cast<const bf16x8*>(xb + (size_t)he * DIM + sl * 8);
                }
            }
            for (int p = 0; p < mx; ++p) {
                bf16x8 ynext[4];
#pragma unroll
                for (int q = 0; q < 4; ++q) {
                    if (p + 1 < ln[q]) {
                        int he = eh[st[q] + p + 1];
                        ynext[q] = *reinterpret_cast<const bf16x8*>(xb + (size_t)he * DIM + sl * 8);
                    }
                }
#pragma unroll
                for (int q = 0; q < 4; ++q) {
                    if (p < ln[q]) {
#pragma unroll
                        for (int k = 0; k < 8; ++k) a[q][k] += (float)ycur[q][k];
                    }
                }
#pragma unroll
                for (int q = 0; q < 4; ++q) ycur[q] = ynext[q];
            }
        }
#pragma unroll
        for (int q = 0; q < 4; ++q) {
            int trow = slot + (q >> 1) * 16;
            float sc = invl[trow * 8 + tp * 2 + (q & 1)];
            bf16x8 out;
#pragma unroll
            for (int k = 0; k < 8; ++k) out[k] = (__bf16)(a[q][k] * sc);
            *reinterpret_cast<bf16x8*>(&Atile[q & 1][trow * PAD + sl * 8]) = out;
        }
        __syncthreads();
#pragma unroll
        for (int u = 0; u < 2; ++u) {
            const __bf16* wterm = wf + (size_t)(tp * 2 + u) * 2048 * 8;
#pragma unroll
            for (int s = 0; s < 4; ++s) {
                bf16x8 af = *reinterpret_cast<const bf16x8*>(&Atile[u][arow * PAD + s * 32 + quad * 8]);
#pragma unroll
                for (int nt = 0; nt < 4; ++nt) {
                    bf16x8 bf = *reinterpret_cast<const bf16x8*>(
                        wterm + (size_t)((s * 8 + ntg0 + nt) * 64 + lane) * 8);
                    C[nt] = __builtin_amdgcn_mfma_f32_16x16x32_bf16(af, bf, C[nt], 0, 0, 0);
                }
            }
        }
        __syncthreads();
    }

    // ---- root term: A row = xb[t] ----
#pragma unroll
    for (int i = 0; i < 2; ++i) {
        int trow = slot + i * 16;
        int t = tbase + trow;
        bf16x8 out;
        if (t < NN) {
            out = *reinterpret_cast<const bf16x8*>(xb + (size_t)t * DIM + sl * 8);
        } else {
#pragma unroll
            for (int j = 0; j < 8; ++j) out[j] = (__bf16)0.f;
        }
        *reinterpret_cast<bf16x8*>(&Atile[0][trow * PAD + sl * 8]) = out;
    }
    __syncthreads();
    {
        const __bf16* wterm = wf + (size_t)8 * 2048 * 8;
#pragma unroll
        for (int s = 0; s < 4; ++s) {
            bf16x8 af = *reinterpret_cast<const bf16x8*>(&Atile[0][arow * PAD + s * 32 + quad * 8]);
#pragma unroll
            for (int nt = 0; nt < 4; ++nt) {
                bf16x8 bf = *reinterpret_cast<const bf16x8*>(
                    wterm + (size_t)((s * 8 + ntg0 + nt) * 64 + lane) * 8);
                C[nt] = __builtin_amdgcn_mfma_f32_16x16x32_bf16(af, bf, C[nt], 0, 0, 0);
            }
        }
    }
    __syncthreads();   // Atile dead -> reuse as reduction scratch

    // ---- epilogue: bias + relu in-register, fused S2/X1 block partials ----
    float* red = reinterpret_cast<float*>(&Atile[0][0]);   // [4][576] = 9.2 KB
    const int rowl0 = (wave & 1) * 16 + quad * 4;
    const int colc = lane & 15;
#pragma unroll
    for (int nt = 0; nt < 4; ++nt) {
        float badd = b1[ntg0 * 16 + nt * 16 + colc];
#pragma unroll
        for (int i = 0; i < 4; ++i) C[nt][i] = fmaxf(C[nt][i] + badd, 0.f);
    }
    float rmask[4];
#pragma unroll
    for (int i = 0; i < 4; ++i) rmask[i] = (tbase + rowl0 + i < NN) ? 1.f : 0.f;
#pragma unroll
    for (int nt = 0; nt < 4; ++nt) {
        float p = rmask[0] * C[nt][0] + rmask[1] * C[nt][1] + rmask[2] * C[nt][2] + rmask[3] * C[nt][3];
        p += __shfl_xor(p, 16);
        p += __shfl_xor(p, 32);
        if (quad == 0) red[wave * 576 + nt * 16 + colc] = p;
    }
#pragma unroll
    for (int rr = 0; rr < NR; ++rr) {
        float w0 = wsl[rr][rowl0], w1 = wsl[rr][rowl0 + 1];
        float w2 = wsl[rr][rowl0 + 2], w3 = wsl[rr][rowl0 + 3];
#pragma unroll
        for (int nt = 0; nt < 4; ++nt) {
            float p = w0 * C[nt][0] + w1 * C[nt][1] + w2 * C[nt][2] + w3 * C[nt][3];
            p += __shfl_xor(p, 16);
            p += __shfl_xor(p, 32);
            if (quad == 0) red[wave * 576 + 64 + rr * 64 + nt * 16 + colc] = p;
        }
    }
    __syncthreads();
    for (int j = tid; j < 1152; j += 256) {
        int rr = j >> 7, c = j & 127;          // rr==8 -> X1
        int u = c >> 6, cc = c & 63;
        int o = (rr < 8) ? (64 + rr * 64 + cc) : cc;
        S2P[(size_t)blockIdx.x * 1152 + j] = red[(u * 2) * 576 + o] + red[(u * 2 + 1) * 576 + o];
    }
}

// ---------------- s2red + final merged: reduce S2P -> S2X1, last block computes out ----------------
__global__ __launch_bounds__(256) void s2redfin_k(
    const float* __restrict__ S2P, float* __restrict__ S2X1, int* __restrict__ done,
    const float* __restrict__ W2, const float* __restrict__ root2,
    const float* __restrict__ b2, float* __restrict__ out)
{
    __shared__ float s2l[1152];
    __shared__ float red2[256];
    __shared__ int isLast;
    const int tid = threadIdx.x;
    int cb = blockIdx.x % 5, stripe = blockIdx.x / 5;
    int c = cb * 256 + tid;
    if (c < 1152) {
        int b0 = stripe * 196, b1 = min(NB, b0 + 196);
        float s0 = 0.f, s1 = 0.f;
        int b = b0;
        for (; b + 1 < b1; b += 2) {
            s0 += S2P[(size_t)b * 1152 + c];
            s1 += S2P[(size_t)(b + 1) * 1152 + c];
        }
        if (b < b1) s0 += S2P[(size_t)b * 1152 + c];
        atomicAdd(&S2X1[c], s0 + s1);
    }
    __threadfence();
    __syncthreads();
    if (tid == 0) {
        int old = atomicAdd(done, 1);
        isLast = (old == 39);
    }
    __syncthreads();
    if (!isLast) return;
    for (int j = tid; j < 1152; j += 256)
        s2l[j] = __hip_atomic_load(&S2X1[j], __ATOMIC_ACQUIRE, __HIP_MEMORY_SCOPE_AGENT);
    __syncthreads();
    const int o = tid & 127, half = tid >> 7;
    float s = 0.f;
    for (int j = half * 576; j < (half + 1) * 576; ++j) {
        float w = (j < 1024) ? W2[(size_t)j * DIM + o] : root2[(size_t)(j - 1024) * DIM + o];
        s += s2l[j] * w;
    }
    red2[tid] = s;
    __syncthreads();
    if (half == 0) out[o] = (red2[o] + red2[o + 128]) * (1.0f / NN) + b2[o];
}

extern "C" void kernel_launch(void* const* d_in, const int* in_sizes, int n_in,
                              void* d_out, int out_size, void* d_ws, size_t ws_size,
                              hipStream_t stream)
{
    const int*   h     = (const int*)d_in[0];
    const int*   r     = (const int*)d_in[1];
    const int*   t     = (const int*)d_in[2];
    const float* x_emb = (const float*)d_in[3];
    const float* W1    = (const float*)d_in[4];
    const float* root1 = (const float*)d_in[5];
    const float* b1    = (const float*)d_in[6];
    const float* W2    = (const float*)d_in[7];
    const float* root2 = (const float*)d_in[8];
    const float* b2    = (const float*)d_in[9];

    float* ws    = (float*)d_ws;
    float* cnt   = ws + OFF_CNT;     // int counts then inv floats in place
    float* wsum  = ws + OFF_WSUM;
    float* S2    = ws + OFF_S2;      // 1024 S2 + 128 X1 contiguous
    int*   part  = (int*)(ws + OFF_PART);
    int*   ppre  = (int*)(ws + OFF_PPRE);
    int*   done  = (int*)(ws + OFF_DONE);
    int*   offs  = (int*)(ws + OFF_OFFS);
    int*   eh    = (int*)(ws + OFF_EH);
    __bf16* xb   = (__bf16*)(ws + OFF_XB);
    __bf16* wf   = (__bf16*)(ws + OFF_WF);
    float* S2P   = ws + OFF_S2P;

    // zero counts + wsum + S2X1 + part/partpre/done (re-poisoned to 0xAA before every timed launch)
    hipMemsetAsync(ws, 0, (size_t)802304 * sizeof(float), stream);

    // merged cast + weight-frag + count
    prep_k<<<1600, 256, 0, stream>>>(x_emb, xb, W1, root1, wf, r, t, (int*)cnt);

    // chunk-local scan + last-block chunk-prefix scan
    scanA_k<<<391, 256, 0, stream>>>((const int*)cnt, cnt, offs, part, ppre, done);

    // merged fill + wsum single edge pass (4 edges/thread)
    fillw_k<<<782, 256, 0, stream>>>(h, r, t, offs, ppre, eh, cnt, wsum);

    // fused layer 1 + layer-2 partials, depth-2-pipelined walks, 5 blocks/CU
    rgcn_fused_k<<<NB, 256, 0, stream>>>(offs, ppre, eh, cnt, xb, wf, b1, wsum, S2P);

    // reduce + final GEMV (last-block pattern)
    s2redfin_k<<<40, 256, 0, stream>>>(S2P, S2, done + 1, W2, root2, b2, (float*)d_out);
}

// Round 14
// 367.195 us; speedup vs baseline: 1.2484x; 1.2362x over previous
//
#include <hip/hip_runtime.h>
#include <hip/hip_bf16.h>

#define NN 50000
#define NR 8
#define DIM 128
#define NE 800000
#define TM 32     // targets per block
#define PAD 136   // A-tile row stride in bf16 (128 + 8): 2-way LDS conflicts only (free)
#define NB 1563   // ceil(NN/TM)

using floatx4 = __attribute__((ext_vector_type(4))) float;
using bf16x8  = __attribute__((ext_vector_type(8))) __bf16;

// ---------------- workspace layout (in floats) ----------------
// zeroed region: [0, 801152) = cnt + wsum + S2X1
#define OFF_CNT   0u         // 400000: int counts -> float inv in place (seg = t*8+r)
#define OFF_WSUM  400000u    // 400000: wsum[r*NN+h] fp32 atomic accum
#define OFF_S2    800000u    // 1024 S2 + 128 X1 (atomic finish by s2red_k)
#define OFF_OFFS  801152u    // 400000 ints: CSR offsets (end-offsets after fillw)
#define OFF_PART  1201152u   // 512 ints: scan partials
#define OFF_EH    1201664u   // 800000 ints: CSR-sorted edge head indices
#define OFF_XB    2001664u   // 6.4M bf16: x_emb in bf16
#define OFF_WF    5201664u   // 9*2048*8 bf16: weights in MFMA frag order
#define OFF_S2P   5275392u   // NB*1152: per-block S2/X1 partials

// ---------------- merged prep: bf16 cast + weight frags + (t,rel) counts ----------------
__global__ __launch_bounds__(256) void prep_k(
    const float* __restrict__ x, __bf16* __restrict__ xb,
    const float* __restrict__ W1, const float* __restrict__ root1, __bf16* __restrict__ wf,
    const int* __restrict__ r, const int* __restrict__ t, int* __restrict__ cnt)
{
    const int gid = blockIdx.x * 256 + threadIdx.x;
    const int nthr = gridDim.x * 256;

    if (gid < 9 * 2048) {
        int mat = gid >> 11, idx = gid & 2047;
        const float* B = (mat < 8) ? (W1 + (size_t)mat * DIM * DIM) : root1;
        int lt = idx & 63, fid = idx >> 6;
        int s = fid >> 3, nt = fid & 7;
        int n = nt * 16 + (lt & 15);
        int kb = s * 32 + (lt >> 4) * 8;
        bf16x8 v;
#pragma unroll
        for (int j = 0; j < 8; ++j) v[j] = (__bf16)B[(kb + j) * DIM + n];
        *reinterpret_cast<bf16x8*>(wf + ((size_t)mat * 2048 + idx) * 8) = v;
    }
    for (int i = gid; i < NN * DIM / 4; i += nthr) {
        int base = i * 4;
        float4 v = *reinterpret_cast<const float4*>(x + base);
        __bf16 o[4] = {(__bf16)v.x, (__bf16)v.y, (__bf16)v.z, (__bf16)v.w};
        *reinterpret_cast<uint2*>(xb + base) = *reinterpret_cast<uint2*>(o);
    }
    for (int i = gid; i < NE / 4; i += nthr) {
        int base = i * 4;
        int4 rv = *reinterpret_cast<const int4*>(r + base);
        int4 tv = *reinterpret_cast<const int4*>(t + base);
        atomicAdd(&cnt[tv.x * NR + rv.x], 1);
        atomicAdd(&cnt[tv.y * NR + rv.y], 1);
        atomicAdd(&cnt[tv.z * NR + rv.z], 1);
        atomicAdd(&cnt[tv.w * NR + rv.w], 1);
    }
}

// ---------------- 3-pass exclusive scan (R10 proven) ----------------
__global__ __launch_bounds__(256) void scanA_k(const int* cnt, float* invout,
                                               int* __restrict__ offs, int* __restrict__ part) {
    __shared__ int lds[256];
    const int tid = threadIdx.x;
    const int base = blockIdx.x * 1024 + tid * 4;
    int v[4] = {0, 0, 0, 0};
    if (base + 3 < NR * NN) {
        int4 q = *reinterpret_cast<const int4*>(cnt + base);
        v[0] = q.x; v[1] = q.y; v[2] = q.z; v[3] = q.w;
    } else {
#pragma unroll
        for (int j = 0; j < 4; ++j) if (base + j < NR * NN) v[j] = cnt[base + j];
    }
    int tsum = v[0] + v[1] + v[2] + v[3];
    lds[tid] = tsum;
    __syncthreads();
#pragma unroll
    for (int off = 1; off < 256; off <<= 1) {
        int val = (tid >= off) ? lds[tid - off] : 0;
        __syncthreads();
        if (tid >= off) lds[tid] += val;
        __syncthreads();
    }
    int run = lds[tid] - tsum;
#pragma unroll
    for (int j = 0; j < 4; ++j) {
        if (base + j < NR * NN) {
            offs[base + j] = run;
            invout[base + j] = 1.0f / (float)(v[j] > 1 ? v[j] : 1);
        }
        run += v[j];
    }
    if (tid == 255) part[blockIdx.x] = lds[255];
}

__global__ __launch_bounds__(512) void scanB_k(int* __restrict__ part) {
    __shared__ int lds[512];
    const int tid = threadIdx.x;
    int v = (tid < 391) ? part[tid] : 0;
    lds[tid] = v;
    __syncthreads();
#pragma unroll
    for (int off = 1; off < 512; off <<= 1) {
        int val = (tid >= off) ? lds[tid - off] : 0;
        __syncthreads();
        if (tid >= off) lds[tid] += val;
        __syncthreads();
    }
    part[tid] = lds[tid] - v;  // exclusive
}

__global__ __launch_bounds__(256) void scanC_k(int* __restrict__ offs, const int* __restrict__ part) {
    const int base = blockIdx.x * 1024 + threadIdx.x * 4;
    const int add = part[blockIdx.x];
#pragma unroll
    for (int j = 0; j < 4; ++j)
        if (base + j < NR * NN) offs[base + j] += add;
}

// ---------------- merged CSR fill + wsum, 4 edges/thread (R10 proven) ----------------
__global__ void fillw_k(const int* __restrict__ h, const int* __restrict__ r, const int* __restrict__ t,
                        int* __restrict__ offs, int* __restrict__ eh,
                        const float* __restrict__ inv, float* __restrict__ wsum) {
    int base = (blockIdx.x * 256 + threadIdx.x) * 4;
    if (base + 3 < NE) {
        int4 hv = *reinterpret_cast<const int4*>(h + base);
        int4 rv = *reinterpret_cast<const int4*>(r + base);
        int4 tv = *reinterpret_cast<const int4*>(t + base);
        int g0 = tv.x * NR + rv.x, g1 = tv.y * NR + rv.y;
        int g2 = tv.z * NR + rv.z, g3 = tv.w * NR + rv.w;
        int p0 = atomicAdd(&offs[g0], 1);
        int p1 = atomicAdd(&offs[g1], 1);
        int p2 = atomicAdd(&offs[g2], 1);
        int p3 = atomicAdd(&offs[g3], 1);
        eh[p0] = hv.x; eh[p1] = hv.y; eh[p2] = hv.z; eh[p3] = hv.w;
        atomicAdd(&wsum[rv.x * NN + hv.x], inv[g0]);
        atomicAdd(&wsum[rv.y * NN + hv.y], inv[g1]);
        atomicAdd(&wsum[rv.z * NN + hv.z], inv[g2]);
        atomicAdd(&wsum[rv.w * NN + hv.w], inv[g3]);
    } else {
        for (int e = base; e < NE; ++e) {
            int he = h[e], re = r[e];
            int seg = t[e] * NR + re;
            int pos = atomicAdd(&offs[seg], 1);
            eh[pos] = he;
            atomicAdd(&wsum[re * NN + he], inv[seg]);
        }
    }
}

// ---------------- fused layer 1 + layer-2 partials, 32-row tiles ----------------
// R11's best rgcn: depth-2 pipelined walks, eh direct from L2 (no eidx staging),
// __launch_bounds__(256,4) — the ONLY config this compiler gives the natural 64
// VGPRs without spilling (R12: (256,6)->40 VGPR+spill; R13: (256,5)->48+spill).
__global__ __launch_bounds__(256, 4) void rgcn_fused_k(
    const int* __restrict__ offs, const int* __restrict__ eh, const float* __restrict__ inv,
    const __bf16* __restrict__ xb, const __bf16* __restrict__ wf,
    const float* __restrict__ b1, const float* __restrict__ wsum,
    float* __restrict__ S2P)
{
    __shared__ __attribute__((aligned(16))) __bf16 Atile[2][TM * PAD];  // 17.4 KB (reused as red[4][576])
    __shared__ int   loffs[TM * NR + 1];
    __shared__ float invl[TM * NR];
    __shared__ float wsl[NR][TM];
    const int tid = threadIdx.x;
    const int wave = tid >> 6, lane = tid & 63, quad = lane >> 4;
    const int slot = tid >> 4, sl = tid & 15;   // 16 gather slots x 16 lanes
    const int tbase = blockIdx.x * TM;
    const int segbase = tbase * NR;

    for (int j = tid; j < TM * NR + 1; j += 256) {
        int g = segbase + j - 1;
        loffs[j] = (g < 0) ? 0 : offs[g > NR * NN - 1 ? NR * NN - 1 : g];
    }
    for (int j = tid; j < TM * NR; j += 256) {
        int g = segbase + j;
        invl[j] = (g < NR * NN) ? inv[g] : 0.f;
    }
    if (tid < NR * TM) {
        int rr = tid >> 5, n = tbase + (tid & 31);
        wsl[rr][tid & 31] = (n < NN) ? wsum[rr * NN + n] : 0.f;
    }
    __syncthreads();

    floatx4 C[4];
#pragma unroll
    for (int i = 0; i < 4; ++i) C[i] = (floatx4)0.f;
    const int arow = (wave & 1) * 16 + (lane & 15);   // wave row-strip
    const int ntg0 = (wave >> 1) * 4;                 // wave col-strip (4 nt each)

    // ---- 4 term-pairs: 4 depth-2-pipelined walks (2 rows x 2 terms), 2 A-tiles ----
    for (int tp = 0; tp < 4; ++tp) {
        int st[4], ln[4];
        float a[4][8];
#pragma unroll
        for (int q = 0; q < 4; ++q) {
            int j = (slot + (q >> 1) * 16) * 8 + tp * 2 + (q & 1);
            st[q] = loffs[j];
            ln[q] = loffs[j + 1] - loffs[j];
#pragma unroll
            for (int k = 0; k < 8; ++k) a[q][k] = 0.f;
        }
        int mx = max(max(ln[0], ln[1]), max(ln[2], ln[3]));
        if (mx > 0) {
            bf16x8 ycur[4];
#pragma unroll
            for (int q = 0; q < 4; ++q) {
                if (0 < ln[q]) {
                    int he = eh[st[q]];
                    ycur[q] = *reinterpret_cast<const bf16x8*>(xb + (size_t)he * DIM + sl * 8);
                }
            }
            for (int p = 0; p < mx; ++p) {
                bf16x8 ynext[4];
#pragma unroll
                for (int q = 0; q < 4; ++q) {
                    if (p + 1 < ln[q]) {
                        int he = eh[st[q] + p + 1];
                        ynext[q] = *reinterpret_cast<const bf16x8*>(xb + (size_t)he * DIM + sl * 8);
                    }
                }
#pragma unroll
                for (int q = 0; q < 4; ++q) {
                    if (p < ln[q]) {
#pragma unroll
                        for (int k = 0; k < 8; ++k) a[q][k] += (float)ycur[q][k];
                    }
                }
#pragma unroll
                for (int q = 0; q < 4; ++q) ycur[q] = ynext[q];
            }
        }
#pragma unroll
        for (int q = 0; q < 4; ++q) {
            int trow = slot + (q >> 1) * 16;
            float sc = invl[trow * 8 + tp * 2 + (q & 1)];
            bf16x8 out;
#pragma unroll
            for (int k = 0; k < 8; ++k) out[k] = (__bf16)(a[q][k] * sc);
            *reinterpret_cast<bf16x8*>(&Atile[q & 1][trow * PAD + sl * 8]) = out;
        }
        __syncthreads();
#pragma unroll
        for (int u = 0; u < 2; ++u) {
            const __bf16* wterm = wf + (size_t)(tp * 2 + u) * 2048 * 8;
#pragma unroll
            for (int s = 0; s < 4; ++s) {
                bf16x8 af = *reinterpret_cast<const bf16x8*>(&Atile[u][arow * PAD + s * 32 + quad * 8]);
#pragma unroll
                for (int nt = 0; nt < 4; ++nt) {
                    bf16x8 bf = *reinterpret_cast<const bf16x8*>(
                        wterm + (size_t)((s * 8 + ntg0 + nt) * 64 + lane) * 8);
                    C[nt] = __builtin_amdgcn_mfma_f32_16x16x32_bf16(af, bf, C[nt], 0, 0, 0);
                }
            }
        }
        __syncthreads();
    }

    // ---- root term: A row = xb[t] ----
#pragma unroll
    for (int i = 0; i < 2; ++i) {
        int trow = slot + i * 16;
        int t = tbase + trow;
        bf16x8 out;
        if (t < NN) {
            out = *reinterpret_cast<const bf16x8*>(xb + (size_t)t * DIM + sl * 8);
        } else {
#pragma unroll
            for (int j = 0; j < 8; ++j) out[j] = (__bf16)0.f;
        }
        *reinterpret_cast<bf16x8*>(&Atile[0][trow * PAD + sl * 8]) = out;
    }
    __syncthreads();
    {
        const __bf16* wterm = wf + (size_t)8 * 2048 * 8;
#pragma unroll
        for (int s = 0; s < 4; ++s) {
            bf16x8 af = *reinterpret_cast<const bf16x8*>(&Atile[0][arow * PAD + s * 32 + quad * 8]);
#pragma unroll
            for (int nt = 0; nt < 4; ++nt) {
                bf16x8 bf = *reinterpret_cast<const bf16x8*>(
                    wterm + (size_t)((s * 8 + ntg0 + nt) * 64 + lane) * 8);
                C[nt] = __builtin_amdgcn_mfma_f32_16x16x32_bf16(af, bf, C[nt], 0, 0, 0);
            }
        }
    }
    __syncthreads();   // Atile dead -> reuse as reduction scratch

    // ---- epilogue: bias + relu in-register, fused S2/X1 block partials ----
    float* red = reinterpret_cast<float*>(&Atile[0][0]);   // [4][576] = 9.2 KB
    const int rowl0 = (wave & 1) * 16 + quad * 4;
    const int colc = lane & 15;
#pragma unroll
    for (int nt = 0; nt < 4; ++nt) {
        float badd = b1[ntg0 * 16 + nt * 16 + colc];
#pragma unroll
        for (int i = 0; i < 4; ++i) C[nt][i] = fmaxf(C[nt][i] + badd, 0.f);
    }
    float rmask[4];
#pragma unroll
    for (int i = 0; i < 4; ++i) rmask[i] = (tbase + rowl0 + i < NN) ? 1.f : 0.f;
#pragma unroll
    for (int nt = 0; nt < 4; ++nt) {
        float p = rmask[0] * C[nt][0] + rmask[1] * C[nt][1] + rmask[2] * C[nt][2] + rmask[3] * C[nt][3];
        p += __shfl_xor(p, 16);
        p += __shfl_xor(p, 32);
        if (quad == 0) red[wave * 576 + nt * 16 + colc] = p;
    }
#pragma unroll
    for (int rr = 0; rr < NR; ++rr) {
        float w0 = wsl[rr][rowl0], w1 = wsl[rr][rowl0 + 1];
        float w2 = wsl[rr][rowl0 + 2], w3 = wsl[rr][rowl0 + 3];
#pragma unroll
        for (int nt = 0; nt < 4; ++nt) {
            float p = w0 * C[nt][0] + w1 * C[nt][1] + w2 * C[nt][2] + w3 * C[nt][3];
            p += __shfl_xor(p, 16);
            p += __shfl_xor(p, 32);
            if (quad == 0) red[wave * 576 + 64 + rr * 64 + nt * 16 + colc] = p;
        }
    }
    __syncthreads();
    for (int j = tid; j < 1152; j += 256) {
        int rr = j >> 7, c = j & 127;          // rr==8 -> X1
        int u = c >> 6, cc = c & 63;
        int o = (rr < 8) ? (64 + rr * 64 + cc) : cc;
        S2P[(size_t)blockIdx.x * 1152 + j] = red[(u * 2) * 576 + o] + red[(u * 2 + 1) * 576 + o];
    }
}

// ---------------- reduce S2P[NB][1152] -> S2X1[1152] (atomic finish, 8 stripes) ----------------
__global__ void s2red_k(const float* __restrict__ S2P, float* __restrict__ S2X1) {
    int cb = blockIdx.x % 5, stripe = blockIdx.x / 5;
    int c = cb * 256 + threadIdx.x;
    if (c >= 1152) return;
    int b0 = stripe * 196, b1 = min(NB, b0 + 196);
    float s0 = 0.f, s1 = 0.f;
    int b = b0;
    for (; b + 1 < b1; b += 2) {
        s0 += S2P[(size_t)b * 1152 + c];
        s1 += S2P[(size_t)(b + 1) * 1152 + c];
    }
    if (b < b1) s0 += S2P[(size_t)b * 1152 + c];
    atomicAdd(&S2X1[c], s0 + s1);
}

// ---------------- final: out = (S2.W2 + X1.root2)/N + b2  (1024 thr, 8-way split) ----------------
__global__ __launch_bounds__(1024) void final_k(
    const float* __restrict__ S2X1, const float* __restrict__ W2,
    const float* __restrict__ root2, const float* __restrict__ b2, float* __restrict__ out)
{
    __shared__ float red[1024];
    const int o = threadIdx.x & 127, c = threadIdx.x >> 7;  // 8 chunks of 144 terms
    float s = 0.f;
    for (int j = c * 144; j < (c + 1) * 144; ++j) {
        float v = S2X1[j];
        float w = (j < 1024) ? W2[(size_t)j * DIM + o] : root2[(size_t)(j - 1024) * DIM + o];
        s += v * w;
    }
    red[threadIdx.x] = s;
    __syncthreads();
    if (c == 0) {
        float tot = 0.f;
#pragma unroll
        for (int k = 0; k < 8; ++k) tot += red[o + 128 * k];
        out[o] = tot * (1.0f / NN) + b2[o];
    }
}

extern "C" void kernel_launch(void* const* d_in, const int* in_sizes, int n_in,
                              void* d_out, int out_size, void* d_ws, size_t ws_size,
                              hipStream_t stream)
{
    const int*   h     = (const int*)d_in[0];
    const int*   r     = (const int*)d_in[1];
    const int*   t     = (const int*)d_in[2];
    const float* x_emb = (const float*)d_in[3];
    const float* W1    = (const float*)d_in[4];
    const float* root1 = (const float*)d_in[5];
    const float* b1    = (const float*)d_in[6];
    const float* W2    = (const float*)d_in[7];
    const float* root2 = (const float*)d_in[8];
    const float* b2    = (const float*)d_in[9];

    float* ws   = (float*)d_ws;
    float* cnt  = ws + OFF_CNT;     // int counts then inv floats in place
    float* wsum = ws + OFF_WSUM;
    float* S2   = ws + OFF_S2;      // 1024 S2 + 128 X1 contiguous
    int*   offs = (int*)(ws + OFF_OFFS);
    int*   part = (int*)(ws + OFF_PART);
    int*   eh   = (int*)(ws + OFF_EH);
    __bf16* xb  = (__bf16*)(ws + OFF_XB);
    __bf16* wf  = (__bf16*)(ws + OFF_WF);
    float* S2P  = ws + OFF_S2P;

    // zero counts + wsum + S2X1 (ws re-poisoned to 0xAA before every timed launch)
    hipMemsetAsync(ws, 0, (size_t)801152 * sizeof(float), stream);

    // merged cast + weight-frag + count
    prep_k<<<1600, 256, 0, stream>>>(x_emb, xb, W1, root1, wf, r, t, (int*)cnt);

    // 3-pass exclusive scan: cnt -> offs (+inv in place)
    scanA_k<<<391, 256, 0, stream>>>((const int*)cnt, cnt, offs, part);
    scanB_k<<<1, 512, 0, stream>>>(part);
    scanC_k<<<391, 256, 0, stream>>>(offs, part);

    // merged fill + wsum single edge pass (4 edges/thread)
    fillw_k<<<782, 256, 0, stream>>>(h, r, t, offs, eh, cnt, wsum);

    // fused layer 1 + layer-2 partials, depth-2-pipelined walks, eh direct
    rgcn_fused_k<<<NB, 256, 0, stream>>>(offs, eh, cnt, xb, wf, b1, wsum, S2P);

    s2red_k<<<40, 256, 0, stream>>>(S2P, S2);
    final_k<<<1, 1024, 0, stream>>>(S2, W2, root2, b2, (float*)d_out);
}